// Round 10
// baseline (352.972 us; speedup 1.0000x reference)
//
#include <hip/hip_runtime.h>
#include <hip/hip_bf16.h>
#include <math.h>

// Problem constants
constexpr int B  = 4;
constexpr int S  = 2048;
constexpr int E  = 1024;
constexpr int H  = 16;
constexpr int DH = 64;
constexpr int M  = B * S;        // 8192 rows when (b,s) flattened

typedef __attribute__((ext_vector_type(8))) short bf16x8;
typedef __attribute__((ext_vector_type(4))) float f32x4;
typedef __attribute__((ext_vector_type(2))) float f32x2;

__device__ __forceinline__ ushort f2bf(float f) {
    union { float f; uint u; } x; x.f = f;
    uint r = x.u + 0x7fffu + ((x.u >> 16) & 1u);   // RNE
    return (ushort)(r >> 16);
}
__device__ __forceinline__ float bf2f(ushort u) {
    union { uint u; float f; } x; x.u = (uint)u << 16;
    return x.f;
}
__device__ __forceinline__ uint cvt_pk_bf16(float lo, float hi) {
    uint r;
    asm("v_cvt_pk_bf16_f32 %0, %1, %2" : "=v"(r) : "v"(lo), "v"(hi));
    return r;
}

__device__ __forceinline__ void gld16(const void* g, void* l) {
    __builtin_amdgcn_global_load_lds(
        (const __attribute__((address_space(1))) void*)g,
        (__attribute__((address_space(3))) void*)l, 16, 0, 0);
}

// ---------------------------------------------------------------------------
// Prep 1: f32 -> bf16 elementwise. grid*256*8 must equal n.
// ---------------------------------------------------------------------------
__global__ __launch_bounds__(256)
void cvt_bf16(const float* __restrict__ in, ushort* __restrict__ out)
{
    size_t i = ((size_t)blockIdx.x * 256 + threadIdx.x) * 8;
    float4 a = *(const float4*)&in[i];
    float4 b = *(const float4*)&in[i + 4];
    ushort4 r0, r1;
    r0.x = f2bf(a.x); r0.y = f2bf(a.y); r0.z = f2bf(a.z); r0.w = f2bf(a.w);
    r1.x = f2bf(b.x); r1.y = f2bf(b.y); r1.z = f2bf(b.z); r1.w = f2bf(b.w);
    *(ushort4*)&out[i]     = r0;
    *(ushort4*)&out[i + 4] = r1;
}

// ---------------------------------------------------------------------------
// Prep 2: pack wq/wk/wv [H][E][DH] f32 -> Bt [(z*H+h)*64 + d][E] bf16
// ---------------------------------------------------------------------------
__global__ __launch_bounds__(256)
void pack_w(const float* __restrict__ wq, const float* __restrict__ wk,
            const float* __restrict__ wv, ushort* __restrict__ Bt)
{
    const int e0 = blockIdx.x * 64;
    const int h  = blockIdx.y;
    const int z  = blockIdx.z;
    const float* w = (z == 0) ? wq : (z == 1) ? wk : wv;

    __shared__ float Ts[64][65];
    const int t = threadIdx.x;
    const int r = t >> 4, c4 = (t & 15) * 4;

    #pragma unroll
    for (int i = 0; i < 4; ++i) {
        float4 a = *(const float4*)&w[((size_t)h * E + e0 + r + i * 16) * DH + c4];
        Ts[r + i * 16][c4 + 0] = a.x; Ts[r + i * 16][c4 + 1] = a.y;
        Ts[r + i * 16][c4 + 2] = a.z; Ts[r + i * 16][c4 + 3] = a.w;
    }
    __syncthreads();
    #pragma unroll
    for (int i = 0; i < 4; ++i) {
        int d = (t >> 4) + i * 16;
        ushort4 o;
        o.x = f2bf(Ts[c4 + 0][d]); o.y = f2bf(Ts[c4 + 1][d]);
        o.z = f2bf(Ts[c4 + 2][d]); o.w = f2bf(Ts[c4 + 3][d]);
        *(ushort4*)&Bt[((size_t)(z * H + h) * 64 + d) * E + e0 + c4] = o;
    }
}

// ---------------------------------------------------------------------------
// bf16 MFMA GEMM, C = A[M][K] . Bt[N][K]^T, K=1024.
// mode 0: scatter bf16 q/k (layout [b,h,s,d], q scaled by 0.125*log2e) and
//         v TRANSPOSED (layout [b,h,d,s], packed 4-wide along s).
// mode 1: f32 y + bias.
// ---------------------------------------------------------------------------
__global__ __launch_bounds__(256)
void gemm_bt(const ushort* __restrict__ A, const ushort* __restrict__ Bt,
             int mode,
             ushort* __restrict__ oq, ushort* __restrict__ okk, ushort* __restrict__ ov,
             float* __restrict__ oy, const float* __restrict__ bias)
{
    constexpr int K = 1024;
    const int n0 = blockIdx.x * 128;
    const int m0 = blockIdx.y * 128;

    __shared__ ushort As[128 * 64];
    __shared__ ushort Bs[128 * 64];

    const int t  = threadIdx.x;
    const int w  = t >> 6, l = t & 63;
    const int wr = w >> 1, wc = w & 1;
    const int lg = l >> 4, lc = l & 15;

    f32x4 acc[4][4] = {};

    const ushort* Ab = A  + (size_t)m0 * K;
    const ushort* Bb = Bt + (size_t)n0 * K;

    for (int k0 = 0; k0 < K; k0 += 64) {
        __syncthreads();
        #pragma unroll
        for (int i = 0; i < 4; ++i) {
            int id  = t + i * 256;          // 0..1023
            int row = id >> 3, col = (id & 7) * 8;
            gld16(Ab + (size_t)row * K + k0 + col, (void*)(As + id * 8));
            gld16(Bb + (size_t)row * K + k0 + col, (void*)(Bs + id * 8));
        }
        asm volatile("s_waitcnt vmcnt(0)" ::: "memory");
        __syncthreads();

        #pragma unroll
        for (int kc = 0; kc < 2; ++kc) {
            bf16x8 af[4], bfr[4];
            #pragma unroll
            for (int f = 0; f < 4; ++f) {
                af[f]  = *(const bf16x8*)&As[(wr * 64 + f * 16 + lc) * 64 + kc * 32 + lg * 8];
                bfr[f] = *(const bf16x8*)&Bs[(wc * 64 + f * 16 + lc) * 64 + kc * 32 + lg * 8];
            }
            #pragma unroll
            for (int fm = 0; fm < 4; ++fm)
                #pragma unroll
                for (int fn = 0; fn < 4; ++fn)
                    acc[fm][fn] = __builtin_amdgcn_mfma_f32_16x16x32_bf16(
                        af[fm], bfr[fn], acc[fm][fn], 0, 0, 0);
        }
    }

    if (mode == 0) {
        #pragma unroll
        for (int fn = 0; fn < 4; ++fn) {
            int nb = n0 + wc * 64 + fn * 16;
            int z  = nb >> 10, h = (nb >> 6) & 15, dbase = nb & 63;
            if (z == 2) {
                // v transposed: [b,h,d,s]; 4 consecutive s pack to ushort4
                #pragma unroll
                for (int fm = 0; fm < 4; ++fm) {
                    int mb = m0 + wr * 64 + fm * 16 + lg * 4;
                    int bb = mb >> 11, s0 = mb & (S - 1);
                    ushort4 r4;
                    r4.x = f2bf(acc[fm][fn][0]); r4.y = f2bf(acc[fm][fn][1]);
                    r4.z = f2bf(acc[fm][fn][2]); r4.w = f2bf(acc[fm][fn][3]);
                    *(ushort4*)&ov[((size_t)(bb * H + h) * DH + dbase + lc) * S + s0] = r4;
                }
            } else {
                ushort* o = (z == 0) ? oq : okk;
                // q pre-scale: (1/sqrt(64)) * log2(e) so softmax can use exp2
                float sc  = (z == 0) ? 0.18033688011112042f : 1.0f;
                #pragma unroll
                for (int fm = 0; fm < 4; ++fm)
                    #pragma unroll
                    for (int r = 0; r < 4; ++r) {
                        int m = m0 + wr * 64 + fm * 16 + lg * 4 + r;
                        int b = m >> 11, s = m & (S - 1);
                        o[((size_t)(b * H + h) * S + s) * DH + dbase + lc] =
                            f2bf(acc[fm][fn][r] * sc);
                    }
            }
        }
    } else {
        #pragma unroll
        for (int fn = 0; fn < 4; ++fn) {
            int n = n0 + wc * 64 + fn * 16 + lc;
            float bv = bias[n];
            #pragma unroll
            for (int fm = 0; fm < 4; ++fm)
                #pragma unroll
                for (int r = 0; r < 4; ++r) {
                    int m = m0 + wr * 64 + fm * 16 + lg * 4 + r;
                    oy[(size_t)m * E + n] = acc[fm][fn][r] + bv;
                }
        }
    }
}

// ---------------------------------------------------------------------------
// Kernel 2: flash attention, bf16 MFMA, no online max, exp2-domain softmax.
// R10: double-buffered K/V staging with counted vmcnt(4) + raw s_barrier
// (loads for tile t+1 stay in flight under tile t's compute — never drain
// to 0 mid-loop). Swapped QK^T; packed f32x2 row-sum; packed P store.
// ---------------------------------------------------------------------------
__global__ __launch_bounds__(256)
void attn_fwd(const ushort* __restrict__ q, const ushort* __restrict__ k,
              const ushort* __restrict__ v, ushort* __restrict__ o)
{
    const int q0 = blockIdx.x * 64;
    const int bh = blockIdx.y;
    const int b  = bh >> 4, h = bh & 15;
    const ushort* Qp = q + (size_t)bh * S * DH;
    const ushort* Kp = k + (size_t)bh * S * DH;
    const ushort* Vp = v + (size_t)bh * DH * S;   // [DH][S]

    __shared__ ushort Ks[2][64 * 64];   // XOR-swizzled [krow][d], double-buffered
    __shared__ ushort Vt[2][64 * 64];   // XOR-swizzled [d][k],   double-buffered
    __shared__ ushort Ps[4 * 16 * 72];  // per-wave P [q][k], stride 72

    const int t  = threadIdx.x;
    const int w  = t >> 6;
    const int l  = t & 63;
    const int lg = l >> 4;
    const int lc = l & 15;

    // staging coords (loop-invariant; rows r and r+32 share swizzle offsets)
    const int rr = t >> 3, c8 = t & 7;
    const int ke = ((c8 * 16) ^ ((rr & 7) << 4)) >> 1;   // K src elem offset
    const int ve = (c8 * 8) ^ ((rr & 7) << 3);           // V src elem offset

    auto STAGE = [&](int kt, int bb) {
        gld16(Kp + (size_t)(kt + rr) * DH + ke,      (void*)(Ks[bb] + t * 8));
        gld16(Kp + (size_t)(kt + rr + 32) * DH + ke, (void*)(Ks[bb] + (t + 256) * 8));
        gld16(Vp + (size_t)rr * S + kt + ve,         (void*)(Vt[bb] + t * 8));
        gld16(Vp + (size_t)(rr + 32) * S + kt + ve,  (void*)(Vt[bb] + (t + 256) * 8));
    };

    bf16x8 aq[2];
    #pragma unroll
    for (int dc = 0; dc < 2; ++dc)
        aq[dc] = *(const bf16x8*)&Qp[(size_t)(q0 + w * 16 + lc) * DH + dc * 32 + lg * 8];

    f32x4 acc[4] = {};          // acc[dt][r]: O[q=lg*4+r][d=dt*16+lc]
    float l_ = 0.f;             // softmax denom for q = lc (all lg copies)

    STAGE(0, 0);
    int cur = 0;
    for (int ti = 0; ti < S / 64; ++ti) {
        // ---- prefetch next tile, wait only for current tile's 4 loads ----
        if (ti < S / 64 - 1) {
            STAGE((ti + 1) * 64, cur ^ 1);
            asm volatile("s_waitcnt vmcnt(4)" ::: "memory");
        } else {
            asm volatile("s_waitcnt vmcnt(0)" ::: "memory");
        }
        __builtin_amdgcn_s_barrier();
        const ushort* Kc = Ks[cur];
        const ushort* Vc = Vt[cur];

        // ---- QK^T, swapped operands: sc[ct][r] = S[q=lc][k=ct*16+lg*4+r] ----
        f32x4 sc[4] = {};
        #pragma unroll
        for (int ct = 0; ct < 4; ++ct) {
            #pragma unroll
            for (int dc = 0; dc < 2; ++dc) {
                int row = ct * 16 + lc;
                int baddr = (row * 128 + dc * 64 + lg * 16) ^ ((row & 7) << 4);
                bf16x8 bk = *(const bf16x8*)((const char*)Kc + baddr);
                sc[ct] = __builtin_amdgcn_mfma_f32_16x16x32_bf16(bk, aq[dc], sc[ct], 0, 0, 0);
            }
        }

        // ---- softmax numerator, P = 2^sc; packed row-sum (q=lc) ----
        f32x2 rs2 = {0.f, 0.f};
        #pragma unroll
        for (int ct = 0; ct < 4; ++ct) {
            #pragma unroll
            for (int r = 0; r < 4; ++r)
                sc[ct][r] = __builtin_exp2f(sc[ct][r]);
            f32x2 a; a[0] = sc[ct][0]; a[1] = sc[ct][1];
            f32x2 c; c[0] = sc[ct][2]; c[1] = sc[ct][3];
            rs2 += a; rs2 += c;
        }
        float rs = rs2[0] + rs2[1];
        rs += __shfl_xor(rs, 16);
        rs += __shfl_xor(rs, 32);
        l_ += rs;

        // ---- P -> per-wave LDS [q=lc][k], packed 8B stores ----
        #pragma unroll
        for (int ct = 0; ct < 4; ++ct) {
            uint2 pk;
            pk.x = cvt_pk_bf16(sc[ct][0], sc[ct][1]);
            pk.y = cvt_pk_bf16(sc[ct][2], sc[ct][3]);
            *(uint2*)&Ps[w * 1152 + lc * 72 + ct * 16 + lg * 4] = pk;
        }

        bf16x8 ap[2];
        #pragma unroll
        for (int kc = 0; kc < 2; ++kc)
            ap[kc] = *(const bf16x8*)&Ps[w * 1152 + lc * 72 + kc * 32 + lg * 8];

        // ---- PV: B-operand read from swizzled Vt [d][k] ----
        #pragma unroll
        for (int dt = 0; dt < 4; ++dt) {
            #pragma unroll
            for (int kc = 0; kc < 2; ++kc) {
                int d = dt * 16 + lc;
                int baddr = (d * 128 + kc * 64 + lg * 16) ^ ((d & 7) << 4);
                bf16x8 bv = *(const bf16x8*)((const char*)Vc + baddr);
                acc[dt] = __builtin_amdgcn_mfma_f32_16x16x32_bf16(ap[kc], bv, acc[dt], 0, 0, 0);
            }
        }
        __builtin_amdgcn_s_barrier();   // all waves done reading buf[cur]
        cur ^= 1;
    }

    // ---- epilogue: redistribute l_ (held for q=lc, needed for q=lg*4+r) ----
    float inv[4];
    #pragma unroll
    for (int r = 0; r < 4; ++r)
        inv[r] = 1.0f / __shfl(l_, lg * 4 + r);
    #pragma unroll
    for (int dt = 0; dt < 4; ++dt)
        #pragma unroll
        for (int r = 0; r < 4; ++r)
            o[((size_t)(b * S + q0 + w * 16 + lg * 4 + r)) * E + h * DH + dt * 16 + lc] =
                f2bf(acc[dt][r] * inv[r]);
}

// ---------------------------------------------------------------------------
extern "C" void kernel_launch(void* const* d_in, const int* in_sizes, int n_in,
                              void* d_out, int out_size, void* d_ws, size_t ws_size,
                              hipStream_t stream)
{
    const float* x  = (const float*)d_in[0];
    const float* wq = (const float*)d_in[1];
    const float* wk = (const float*)d_in[2];
    const float* wv = (const float*)d_in[3];
    const float* wo = (const float*)d_in[4];
    const float* bo = (const float*)d_in[5];
    float* out = (float*)d_out;

    const size_t plane = (size_t)B * H * S * DH;   // 8.4M elements
    ushort* xb  = (ushort*)d_ws;                   // [M][E]
    ushort* wt  = xb  + (size_t)M * E;             // [3*H*64][E]
    ushort* wob = wt  + (size_t)3 * H * 64 * E;    // [E][E]
    ushort* q   = wob + (size_t)E * E;
    ushort* k   = q + plane;
    ushort* v   = k + plane;                       // [B,H,DH,S] (transposed)
    ushort* att = v + plane;                       // [M][E]

    // prep
    cvt_bf16<<<dim3((M * E) / 2048), 256, 0, stream>>>(x, xb);
    cvt_bf16<<<dim3((E * E) / 2048), 256, 0, stream>>>(wo, wob);
    pack_w<<<dim3(E / 64, H, 3), 256, 0, stream>>>(wq, wk, wv, wt);

    // QKV projection: [8192 x 1024] . [3072 x 1024]^T
    gemm_bt<<<dim3(3 * E / 128, M / 128), 256, 0, stream>>>(
        xb, wt, 0, q, k, v, nullptr, nullptr);

    attn_fwd<<<dim3(S / 64, B * H), 256, 0, stream>>>(q, k, v, att);

    // output projection: [8192 x 1024] . [1024 x 1024]^T + bias
    gemm_bt<<<dim3(E / 128, M / 128), 256, 0, stream>>>(
        att, wob, 1, nullptr, nullptr, nullptr, out, bo);
}

// Round 12
// 336.028 us; speedup vs baseline: 1.0504x; 1.0504x over previous
//
#include <hip/hip_runtime.h>
#include <hip/hip_bf16.h>
#include <math.h>

// Problem constants
constexpr int B  = 4;
constexpr int S  = 2048;
constexpr int E  = 1024;
constexpr int H  = 16;
constexpr int DH = 64;
constexpr int M  = B * S;        // 8192 rows when (b,s) flattened

typedef __attribute__((ext_vector_type(8))) short bf16x8;
typedef __attribute__((ext_vector_type(4))) float f32x4;

__device__ __forceinline__ ushort f2bf(float f) {
    union { float f; uint u; } x; x.f = f;
    uint r = x.u + 0x7fffu + ((x.u >> 16) & 1u);   // RNE
    return (ushort)(r >> 16);
}
__device__ __forceinline__ float bf2f(ushort u) {
    union { uint u; float f; } x; x.u = (uint)u << 16;
    return x.f;
}
__device__ __forceinline__ uint cvt_pk_bf16(float lo, float hi) {
    uint r;
    asm("v_cvt_pk_bf16_f32 %0, %1, %2" : "=v"(r) : "v"(lo), "v"(hi));
    return r;
}

__device__ __forceinline__ void gld16(const void* g, void* l) {
    __builtin_amdgcn_global_load_lds(
        (const __attribute__((address_space(1))) void*)g,
        (__attribute__((address_space(3))) void*)l, 16, 0, 0);
}

// ---------------------------------------------------------------------------
// Prep 1: f32 -> bf16 elementwise. grid*256*8 must equal n.
// ---------------------------------------------------------------------------
__global__ __launch_bounds__(256)
void cvt_bf16(const float* __restrict__ in, ushort* __restrict__ out)
{
    size_t i = ((size_t)blockIdx.x * 256 + threadIdx.x) * 8;
    float4 a = *(const float4*)&in[i];
    float4 b = *(const float4*)&in[i + 4];
    ushort4 r0, r1;
    r0.x = f2bf(a.x); r0.y = f2bf(a.y); r0.z = f2bf(a.z); r0.w = f2bf(a.w);
    r1.x = f2bf(b.x); r1.y = f2bf(b.y); r1.z = f2bf(b.z); r1.w = f2bf(b.w);
    *(ushort4*)&out[i]     = r0;
    *(ushort4*)&out[i + 4] = r1;
}

// ---------------------------------------------------------------------------
// Prep 2: pack wq/wk/wv [H][E][DH] f32 -> Bt [(z*H+h)*64 + d][E] bf16
// ---------------------------------------------------------------------------
__global__ __launch_bounds__(256)
void pack_w(const float* __restrict__ wq, const float* __restrict__ wk,
            const float* __restrict__ wv, ushort* __restrict__ Bt)
{
    const int e0 = blockIdx.x * 64;
    const int h  = blockIdx.y;
    const int z  = blockIdx.z;
    const float* w = (z == 0) ? wq : (z == 1) ? wk : wv;

    __shared__ float Ts[64][65];
    const int t = threadIdx.x;
    const int r = t >> 4, c4 = (t & 15) * 4;

    #pragma unroll
    for (int i = 0; i < 4; ++i) {
        float4 a = *(const float4*)&w[((size_t)h * E + e0 + r + i * 16) * DH + c4];
        Ts[r + i * 16][c4 + 0] = a.x; Ts[r + i * 16][c4 + 1] = a.y;
        Ts[r + i * 16][c4 + 2] = a.z; Ts[r + i * 16][c4 + 3] = a.w;
    }
    __syncthreads();
    #pragma unroll
    for (int i = 0; i < 4; ++i) {
        int d = (t >> 4) + i * 16;
        ushort4 o;
        o.x = f2bf(Ts[c4 + 0][d]); o.y = f2bf(Ts[c4 + 1][d]);
        o.z = f2bf(Ts[c4 + 2][d]); o.w = f2bf(Ts[c4 + 3][d]);
        *(ushort4*)&Bt[((size_t)(z * H + h) * 64 + d) * E + e0 + c4] = o;
    }
}

// ---------------------------------------------------------------------------
// bf16 MFMA GEMM, C = A[M][K] . Bt[N][K]^T, K=1024.
// T1 XCD-aware bijective block swizzle (grid % 8 == 0 for all launches).
// mode 0: scatter bf16 q/k (layout [b,h,s,d], q scaled by 0.125*log2e) and
//         v TRANSPOSED (layout [b,h,d,s], packed 4-wide along s).
// mode 1: f32 y + bias.
// ---------------------------------------------------------------------------
__global__ __launch_bounds__(256)
void gemm_bt(const ushort* __restrict__ A, const ushort* __restrict__ Bt,
             int mode,
             ushort* __restrict__ oq, ushort* __restrict__ okk, ushort* __restrict__ ov,
             float* __restrict__ oy, const float* __restrict__ bias)
{
    constexpr int K = 1024;
    // XCD swizzle: consecutive work-ids land on one XCD (L2 locality)
    const int nbx = gridDim.x;
    const int bid = blockIdx.y * nbx + blockIdx.x;
    const int cpx = (nbx * gridDim.y) >> 3;
    const int swz = (bid & 7) * cpx + (bid >> 3);
    const int n0 = (swz % nbx) * 128;
    const int m0 = (swz / nbx) * 128;

    __shared__ ushort As[128 * 64];
    __shared__ ushort Bs[128 * 64];

    const int t  = threadIdx.x;
    const int w  = t >> 6, l = t & 63;
    const int wr = w >> 1, wc = w & 1;
    const int lg = l >> 4, lc = l & 15;

    f32x4 acc[4][4] = {};

    const ushort* Ab = A  + (size_t)m0 * K;
    const ushort* Bb = Bt + (size_t)n0 * K;

    for (int k0 = 0; k0 < K; k0 += 64) {
        __syncthreads();
        #pragma unroll
        for (int i = 0; i < 4; ++i) {
            int id  = t + i * 256;          // 0..1023
            int row = id >> 3, col = (id & 7) * 8;
            gld16(Ab + (size_t)row * K + k0 + col, (void*)(As + id * 8));
            gld16(Bb + (size_t)row * K + k0 + col, (void*)(Bs + id * 8));
        }
        asm volatile("s_waitcnt vmcnt(0)" ::: "memory");
        __syncthreads();

        #pragma unroll
        for (int kc = 0; kc < 2; ++kc) {
            bf16x8 af[4], bfr[4];
            #pragma unroll
            for (int f = 0; f < 4; ++f) {
                af[f]  = *(const bf16x8*)&As[(wr * 64 + f * 16 + lc) * 64 + kc * 32 + lg * 8];
                bfr[f] = *(const bf16x8*)&Bs[(wc * 64 + f * 16 + lc) * 64 + kc * 32 + lg * 8];
            }
            #pragma unroll
            for (int fm = 0; fm < 4; ++fm)
                #pragma unroll
                for (int fn = 0; fn < 4; ++fn)
                    acc[fm][fn] = __builtin_amdgcn_mfma_f32_16x16x32_bf16(
                        af[fm], bfr[fn], acc[fm][fn], 0, 0, 0);
        }
    }

    if (mode == 0) {
        #pragma unroll
        for (int fn = 0; fn < 4; ++fn) {
            int nb = n0 + wc * 64 + fn * 16;
            int z  = nb >> 10, h = (nb >> 6) & 15, dbase = nb & 63;
            if (z == 2) {
                // v transposed: [b,h,d,s]; 4 consecutive s pack to ushort4
                #pragma unroll
                for (int fm = 0; fm < 4; ++fm) {
                    int mb = m0 + wr * 64 + fm * 16 + lg * 4;
                    int bb = mb >> 11, s0 = mb & (S - 1);
                    ushort4 r4;
                    r4.x = f2bf(acc[fm][fn][0]); r4.y = f2bf(acc[fm][fn][1]);
                    r4.z = f2bf(acc[fm][fn][2]); r4.w = f2bf(acc[fm][fn][3]);
                    *(ushort4*)&ov[((size_t)(bb * H + h) * DH + dbase + lc) * S + s0] = r4;
                }
            } else {
                ushort* o = (z == 0) ? oq : okk;
                // q pre-scale: (1/sqrt(64)) * log2(e) so softmax can use exp2
                float sc  = (z == 0) ? 0.18033688011112042f : 1.0f;
                #pragma unroll
                for (int fm = 0; fm < 4; ++fm)
                    #pragma unroll
                    for (int r = 0; r < 4; ++r) {
                        int m = m0 + wr * 64 + fm * 16 + lg * 4 + r;
                        int b = m >> 11, s = m & (S - 1);
                        o[((size_t)(b * H + h) * S + s) * DH + dbase + lc] =
                            f2bf(acc[fm][fn][r] * sc);
                    }
            }
        }
    } else {
        #pragma unroll
        for (int fn = 0; fn < 4; ++fn) {
            int n = n0 + wc * 64 + fn * 16 + lc;
            float bv = bias[n];
            #pragma unroll
            for (int fm = 0; fm < 4; ++fm)
                #pragma unroll
                for (int r = 0; r < 4; ++r) {
                    int m = m0 + wr * 64 + fm * 16 + lg * 4 + r;
                    oy[(size_t)m * E + n] = acc[fm][fn][r] + bv;
                }
        }
    }
}

// ---------------------------------------------------------------------------
// Kernel 2: flash attention, bf16 MFMA, no online max, exp2-domain softmax.
// R8 structure (single-buffer, __syncthreads — verified 151 us) + T1 XCD
// swizzle: XCD c gets 8 whole heads; their K/V (4 MB) fit its private L2.
// ---------------------------------------------------------------------------
__global__ __launch_bounds__(256)
void attn_fwd(const ushort* __restrict__ q, const ushort* __restrict__ k,
              const ushort* __restrict__ v, ushort* __restrict__ o)
{
    // grid = (32, 64) -> 2048 blocks; swizzle maps XCD c to heads [c*8, c*8+8)
    const int bid = blockIdx.y * 32 + blockIdx.x;
    const int swz = (bid & 7) * 256 + (bid >> 3);
    const int q0 = (swz & 31) * 64;
    const int bh = swz >> 5;
    const int b  = bh >> 4, h = bh & 15;
    const ushort* Qp = q + (size_t)bh * S * DH;
    const ushort* Kp = k + (size_t)bh * S * DH;
    const ushort* Vp = v + (size_t)bh * DH * S;   // [DH][S]

    __shared__ ushort Ks[64 * 64];      // XOR-swizzled [krow][d]
    __shared__ ushort Vt[64 * 64];      // XOR-swizzled [d][k]
    __shared__ ushort Ps[4 * 16 * 72];  // per-wave P [q][k], stride 72

    const int t  = threadIdx.x;
    const int w  = t >> 6;
    const int l  = t & 63;
    const int lg = l >> 4;
    const int lc = l & 15;

    bf16x8 aq[2];
    #pragma unroll
    for (int dc = 0; dc < 2; ++dc)
        aq[dc] = *(const bf16x8*)&Qp[(size_t)(q0 + w * 16 + lc) * DH + dc * 32 + lg * 8];

    f32x4 acc[4] = {};          // acc[dt][r]: O[q=lg*4+r][d=dt*16+lc]
    float l_ = 0.f;             // softmax denom for q = lc (all lg copies)

    for (int kt = 0; kt < S; kt += 64) {
        __syncthreads();   // previous iteration's LDS reads complete
        // ---- stage K and V (async direct-to-LDS, pre-swizzled sources) ----
        #pragma unroll
        for (int i = 0; i < 2; ++i) {
            int id = t + i * 256;                      // 0..511
            int rr = id >> 3, c8 = id & 7;             // row 0..63, chunk 0..7
            int ke = ((c8 * 16) ^ ((rr & 7) << 4)) >> 1;   // K src elem offset
            gld16(Kp + (size_t)(kt + rr) * DH + ke, (void*)(Ks + id * 8));
            int ve = (c8 * 8) ^ ((rr & 7) << 3);           // V src elem offset
            gld16(Vp + (size_t)rr * S + kt + ve, (void*)(Vt + id * 8));
        }
        asm volatile("s_waitcnt vmcnt(0)" ::: "memory");
        __syncthreads();

        // ---- QK^T, swapped operands: sc[ct][r] = S[q=lc][k=ct*16+lg*4+r] ----
        f32x4 sc[4] = {};
        #pragma unroll
        for (int ct = 0; ct < 4; ++ct) {
            #pragma unroll
            for (int dc = 0; dc < 2; ++dc) {
                int row = ct * 16 + lc;
                int baddr = (row * 128 + dc * 64 + lg * 16) ^ ((row & 7) << 4);
                bf16x8 bk = *(const bf16x8*)((const char*)Ks + baddr);
                sc[ct] = __builtin_amdgcn_mfma_f32_16x16x32_bf16(bk, aq[dc], sc[ct], 0, 0, 0);
            }
        }

        // ---- softmax numerator, P = 2^sc; scalar row-sum (q=lc) ----
        float rs = 0.f;
        #pragma unroll
        for (int ct = 0; ct < 4; ++ct)
            #pragma unroll
            for (int r = 0; r < 4; ++r) {
                float e = __builtin_exp2f(sc[ct][r]);
                sc[ct][r] = e;
                rs += e;
            }
        rs += __shfl_xor(rs, 16);
        rs += __shfl_xor(rs, 32);
        l_ += rs;

        // ---- P -> per-wave LDS [q=lc][k], packed 8B stores ----
        #pragma unroll
        for (int ct = 0; ct < 4; ++ct) {
            uint2 pk;
            pk.x = cvt_pk_bf16(sc[ct][0], sc[ct][1]);
            pk.y = cvt_pk_bf16(sc[ct][2], sc[ct][3]);
            *(uint2*)&Ps[w * 1152 + lc * 72 + ct * 16 + lg * 4] = pk;
        }

        bf16x8 ap[2];
        #pragma unroll
        for (int kc = 0; kc < 2; ++kc)
            ap[kc] = *(const bf16x8*)&Ps[w * 1152 + lc * 72 + kc * 32 + lg * 8];

        // ---- PV: B-operand read from swizzled Vt [d][k] ----
        #pragma unroll
        for (int dt = 0; dt < 4; ++dt) {
            #pragma unroll
            for (int kc = 0; kc < 2; ++kc) {
                int d = dt * 16 + lc;
                int baddr = (d * 128 + kc * 64 + lg * 16) ^ ((d & 7) << 4);
                bf16x8 bv = *(const bf16x8*)((const char*)Vt + baddr);
                acc[dt] = __builtin_amdgcn_mfma_f32_16x16x32_bf16(ap[kc], bv, acc[dt], 0, 0, 0);
            }
        }
    }

    // ---- epilogue: redistribute l_ (held for q=lc, needed for q=lg*4+r) ----
    float inv[4];
    #pragma unroll
    for (int r = 0; r < 4; ++r)
        inv[r] = 1.0f / __shfl(l_, lg * 4 + r);
    #pragma unroll
    for (int dt = 0; dt < 4; ++dt)
        #pragma unroll
        for (int r = 0; r < 4; ++r)
            o[((size_t)(b * S + q0 + w * 16 + lg * 4 + r)) * E + h * DH + dt * 16 + lc] =
                f2bf(acc[dt][r] * inv[r]);
}

// ---------------------------------------------------------------------------
extern "C" void kernel_launch(void* const* d_in, const int* in_sizes, int n_in,
                              void* d_out, int out_size, void* d_ws, size_t ws_size,
                              hipStream_t stream)
{
    const float* x  = (const float*)d_in[0];
    const float* wq = (const float*)d_in[1];
    const float* wk = (const float*)d_in[2];
    const float* wv = (const float*)d_in[3];
    const float* wo = (const float*)d_in[4];
    const float* bo = (const float*)d_in[5];
    float* out = (float*)d_out;

    const size_t plane = (size_t)B * H * S * DH;   // 8.4M elements
    ushort* xb  = (ushort*)d_ws;                   // [M][E]
    ushort* wt  = xb  + (size_t)M * E;             // [3*H*64][E]
    ushort* wob = wt  + (size_t)3 * H * 64 * E;    // [E][E]
    ushort* q   = wob + (size_t)E * E;
    ushort* k   = q + plane;
    ushort* v   = k + plane;                       // [B,H,DH,S] (transposed)
    ushort* att = v + plane;                       // [M][E]

    // prep
    cvt_bf16<<<dim3((M * E) / 2048), 256, 0, stream>>>(x, xb);
    cvt_bf16<<<dim3((E * E) / 2048), 256, 0, stream>>>(wo, wob);
    pack_w<<<dim3(E / 64, H, 3), 256, 0, stream>>>(wq, wk, wv, wt);

    // QKV projection: [8192 x 1024] . [3072 x 1024]^T
    gemm_bt<<<dim3(3 * E / 128, M / 128), 256, 0, stream>>>(
        xb, wt, 0, q, k, v, nullptr, nullptr);

    attn_fwd<<<dim3(S / 64, B * H), 256, 0, stream>>>(q, k, v, att);

    // output projection: [8192 x 1024] . [1024 x 1024]^T + bias
    gemm_bt<<<dim3(E / 128, M / 128), 256, 0, stream>>>(
        att, wob, 1, nullptr, nullptr, nullptr, out, bo);
}